// Round 5
// baseline (34.929 us; speedup 1.0000x reference)
//
#include <hip/hip_runtime.h>

namespace {
constexpr float GRIDSZ = 0.4f;
constexpr float PCX = -40.0f, PCY = -40.0f, PCZ = -1.0f;
constexpr int CCH = 18;        // semantic channels
constexpr int CELLS_X = 25;    // 200 voxels / 8 per xy-cell (z not binned, D=16)
constexpr int NCELLS = CELLS_X * CELLS_X;  // 625
constexpr int VMAX = 199;      // max voxel index in x,y
constexpr int PCAP = 128;      // per-cell point cap (mean ~26, Poisson max ~60)
constexpr int GCAP = 128;      // per-cell candidate cap (mean ~28)
constexpr int SEMW = 20;       // padded semantic row in LDS (80 B)
}

// ONE kernel: each block owns one 8x8-voxel xy cell. It scans pts/means/scales
// (L2-resident), compacts its points + candidate gaussians via LDS atomics,
// rank-sorts candidates (deterministic FP order), builds payloads in LDS, then
// runs the dense little point x candidate loop. No workspace, no global atomics.
__global__ __launch_bounds__(256) void fused_kernel(
    const float* __restrict__ pts, const float* __restrict__ means,
    const float* __restrict__ opac, const float* __restrict__ scales,
    const float* __restrict__ cov, const float* __restrict__ sem,
    float* __restrict__ out, int N, int M) {
  __shared__ int pcnt_s, gcnt_s;
  __shared__ float4 lpts[PCAP];
  __shared__ int graw[GCAP];
  __shared__ int gsrt[GCAP];
  __shared__ int4 lbox[GCAP];
  __shared__ float4 lpay[GCAP * 3];
  __shared__ float lsem[GCAP * SEMW];
  __shared__ float buf[3][64][CCH + 1];  // +1 pad -> 19-word lane stride

  const int tid = threadIdx.x, lane = tid & 63, wave = tid >> 6;
  const int cell = blockIdx.x;
  const int cx = cell % CELLS_X, cy = cell / CELLS_X;

  if (tid == 0) { pcnt_s = 0; gcnt_s = 0; }
  __syncthreads();

  // Phase A: scan all points, keep ours (predicated LDS-atomic compact).
  for (int i = tid; i < N; i += 256) {
    float px = pts[(size_t)i * 3 + 0];
    float py = pts[(size_t)i * 3 + 1];
    float pz = pts[(size_t)i * 3 + 2];
    // must match numpy floor((x-pc_min)/GRID) in f32 exactly
    int pvx = (int)floorf((px - PCX) / GRIDSZ);
    int pvy = (int)floorf((py - PCY) / GRIDSZ);
    if ((pvx >> 3) == cx && (pvy >> 3) == cy) {
      int slot = atomicAdd(&pcnt_s, 1);
      if (slot < PCAP) lpts[slot] = make_float4(px, py, pz, __int_as_float(i));
    }
  }
  // Phase B: scan all gaussians, keep those whose voxel box overlaps this cell.
  for (int g = tid; g < M; g += 256) {
    float mx = means[(size_t)g * 3 + 0];
    float my = means[(size_t)g * 3 + 1];
    float sx = scales[(size_t)g * 3 + 0];
    float sy = scales[(size_t)g * 3 + 1];
    float sz = scales[(size_t)g * 3 + 2];
    int mvx = (int)floorf((mx - PCX) / GRIDSZ);
    int mvy = (int)floorf((my - PCY) / GRIDSZ);
    float smax = fmaxf(sx, fmaxf(sy, sz));
    int r = (int)ceilf(smax * 3.0f / GRIDSZ);
    int cx0 = max(mvx - r, 0) >> 3, cx1 = min(mvx + r, VMAX) >> 3;
    int cy0 = max(mvy - r, 0) >> 3, cy1 = min(mvy + r, VMAX) >> 3;
    if (cx >= cx0 && cx <= cx1 && cy >= cy0 && cy <= cy1) {
      int slot = atomicAdd(&gcnt_s, 1);
      if (slot < GCAP) graw[slot] = g;
    }
  }
  __syncthreads();
  const int P = min(pcnt_s, PCAP);
  const int K = min(gcnt_s, GCAP);

  // rank-sort ascending (indices distinct -> deterministic permutation)
  if (tid < K) {
    int v = graw[tid], rank = 0;
    for (int j = 0; j < K; ++j) rank += (graw[j] < v);
    gsrt[rank] = v;
  }
  __syncthreads();

  // Phase C: thread j builds candidate j's box + inverse-covariance payload.
  if (tid < K) {
    int g = gsrt[tid];
    float mx = means[(size_t)g * 3 + 0];
    float my = means[(size_t)g * 3 + 1];
    float mz = means[(size_t)g * 3 + 2];
    float sx = scales[(size_t)g * 3 + 0];
    float sy = scales[(size_t)g * 3 + 1];
    float sz = scales[(size_t)g * 3 + 2];
    int mvx = (int)floorf((mx - PCX) / GRIDSZ);
    int mvy = (int)floorf((my - PCY) / GRIDSZ);
    int mvz = (int)floorf((mz - PCZ) / GRIDSZ);
    float smax = fmaxf(sx, fmaxf(sy, sz));
    int r = (int)ceilf(smax * 3.0f / GRIDSZ);
    lbox[tid] = make_int4(mvx - r, mvy - r, mvz - r, 2 * r);
    const float* c = cov + (size_t)g * 9;
    float c00 = c[0], c01 = c[1], c02 = c[2], c11 = c[4], c12 = c[5], c22 = c[8];
    float M00 = c11 * c22 - c12 * c12;
    float M01 = c02 * c12 - c01 * c22;
    float M02 = c01 * c12 - c02 * c11;
    float inv = 1.0f / (c00 * M00 + c01 * M01 + c02 * M02);
    lpay[tid * 3 + 0] = make_float4(mx, my, mz, opac[g]);
    lpay[tid * 3 + 1] = make_float4(M00 * inv, M01 * inv, M02 * inv,
                                    (c00 * c22 - c02 * c02) * inv);
    lpay[tid * 3 + 2] = make_float4((c01 * c02 - c00 * c12) * inv,
                                    (c00 * c11 - c01 * c01) * inv, 0.f, 0.f);
  }
  for (int idx = tid; idx < K * CCH; idx += 256) {
    int j = idx / CCH, c2 = idx - j * CCH;
    lsem[j * SEMW + c2] = sem[(size_t)gsrt[j] * CCH + c2];
  }
  __syncthreads();

  // Phase D: candidate range per wave (sorted quarters -> deterministic order).
  const int kq = (K + 3) >> 2;
  const int j0 = wave * kq, j1 = min(K, j0 + kq);

  for (int pb = 0; pb < P; pb += 64) {
    const bool vp = (pb + lane) < P;
    const float4 pt = lpts[vp ? pb + lane : 0];
    int pvx = (int)floorf((pt.x - PCX) / GRIDSZ);
    int pvy = (int)floorf((pt.y - PCY) / GRIDSZ);
    int pvz = (int)floorf((pt.z - PCZ) / GRIDSZ);
    if (!vp) pvx = -100000;  // fails every box

    float acc[CCH];
#pragma unroll
    for (int c = 0; c < CCH; ++c) acc[c] = 0.f;

    for (int j = j0; j < j1; ++j) {
      int4 bx = lbox[j];  // uniform -> LDS broadcast
      bool m = ((unsigned)(pvx - bx.x) <= (unsigned)bx.w) &
               ((unsigned)(pvy - bx.y) <= (unsigned)bx.w) &
               ((unsigned)(pvz - bx.z) <= (unsigned)bx.w);
      if (__any(m)) {
        float4 q0 = lpay[j * 3 + 0];
        float4 q1 = lpay[j * 3 + 1];
        float4 q2 = lpay[j * 3 + 2];
        float dx = pt.x - q0.x, dy = pt.y - q0.y, dz = pt.z - q0.z;
        float t0 = q1.x * dx + q1.y * dy + q1.z * dz;
        float t1 = q1.y * dx + q1.w * dy + q2.x * dz;
        float t2 = q1.z * dx + q2.x * dy + q2.y * dz;
        float qq = dx * t0 + dy * t1 + dz * t2;
        float w = m ? __expf(-0.5f * qq) * q0.w : 0.f;
        const float4* s4 = reinterpret_cast<const float4*>(&lsem[j * SEMW]);
        float4 sa = s4[0], sb = s4[1], sc = s4[2], sd = s4[3];
        float2 se = *reinterpret_cast<const float2*>(&lsem[j * SEMW + 16]);
        acc[0]  = fmaf(w, sa.x, acc[0]);  acc[1]  = fmaf(w, sa.y, acc[1]);
        acc[2]  = fmaf(w, sa.z, acc[2]);  acc[3]  = fmaf(w, sa.w, acc[3]);
        acc[4]  = fmaf(w, sb.x, acc[4]);  acc[5]  = fmaf(w, sb.y, acc[5]);
        acc[6]  = fmaf(w, sb.z, acc[6]);  acc[7]  = fmaf(w, sb.w, acc[7]);
        acc[8]  = fmaf(w, sc.x, acc[8]);  acc[9]  = fmaf(w, sc.y, acc[9]);
        acc[10] = fmaf(w, sc.z, acc[10]); acc[11] = fmaf(w, sc.w, acc[11]);
        acc[12] = fmaf(w, sd.x, acc[12]); acc[13] = fmaf(w, sd.y, acc[13]);
        acc[14] = fmaf(w, sd.z, acc[14]); acc[15] = fmaf(w, sd.w, acc[15]);
        acc[16] = fmaf(w, se.x, acc[16]); acc[17] = fmaf(w, se.y, acc[17]);
      }
    }

    // deterministic cross-wave reduce, one coalesced write per point
    if (wave > 0) {
#pragma unroll
      for (int c = 0; c < CCH; ++c) buf[wave - 1][lane][c] = acc[c];
    }
    __syncthreads();
    if (wave == 0 && vp) {
      int myp = __float_as_int(pt.w);
      float* o = out + (size_t)myp * CCH;
#pragma unroll
      for (int c = 0; c < CCH; ++c)
        o[c] = acc[c] + buf[0][lane][c] + buf[1][lane][c] + buf[2][lane][c];
    }
    __syncthreads();  // buf reused by next point-chunk
  }
}

extern "C" void kernel_launch(void* const* d_in, const int* in_sizes, int n_in,
                              void* d_out, int out_size, void* d_ws, size_t ws_size,
                              hipStream_t stream) {
  const float* pts     = (const float*)d_in[0];
  const float* means3D = (const float*)d_in[1];
  const float* opac    = (const float*)d_in[2];
  const float* sem     = (const float*)d_in[3];
  const float* scales  = (const float*)d_in[4];
  const float* cov3D   = (const float*)d_in[5];
  float* out = (float*)d_out;

  int N = in_sizes[0] / 3;
  int M = in_sizes[1] / 3;

  fused_kernel<<<NCELLS, 256, 0, stream>>>(
      pts, means3D, opac, scales, cov3D, sem, out, N, M);
}

// Round 6
// 26.154 us; speedup vs baseline: 1.3355x; 1.3355x over previous
//
#include <hip/hip_runtime.h>

namespace {
constexpr float GRIDSZ = 0.4f;
constexpr float PCX = -40.0f, PCY = -40.0f, PCZ = -1.0f;
constexpr int CCH = 18;        // semantic channels
constexpr int CELLS_X = 25;    // 200 voxels / 8 per xy-cell (z not binned, D=16)
constexpr int NCELLS = CELLS_X * CELLS_X;  // 625
constexpr int VMAX = 199;      // max voxel index in x,y
constexpr int PCAP = 128;      // per-cell point cap (mean ~26; validated <=128 by passing runs)
constexpr int GCAP = 128;      // per-cell candidate cap (mean ~28)
constexpr int SEMW = 20;       // padded semantic row in LDS (80 B)
}

// Pass 1 (pure, no atomics): per-point packed descriptor + position; per-gaussian
// packed cell-box, voxel box, and inverse-covariance payload. Every IEEE f32
// division (must match numpy bitwise) is computed exactly once here.
__global__ __launch_bounds__(256) void prep_kernel(
    const float* __restrict__ pts, const float* __restrict__ means,
    const float* __restrict__ opac, const float* __restrict__ scales,
    const float* __restrict__ cov,
    unsigned* __restrict__ ppack, float4* __restrict__ ppos,
    unsigned* __restrict__ gcb, int4* __restrict__ gbox,
    float4* __restrict__ gpay, int N, int M) {
  int id = blockIdx.x * 256 + threadIdx.x;
  if (id < M) {
    int g = id;
    float mx = means[(size_t)g * 3 + 0], my = means[(size_t)g * 3 + 1], mz = means[(size_t)g * 3 + 2];
    const float* c = cov + (size_t)g * 9;
    float c00 = c[0], c01 = c[1], c02 = c[2], c11 = c[4], c12 = c[5], c22 = c[8];
    float M00 = c11 * c22 - c12 * c12;
    float M01 = c02 * c12 - c01 * c22;
    float M02 = c01 * c12 - c02 * c11;
    float inv = 1.0f / (c00 * M00 + c01 * M01 + c02 * M02);
    int mvx = (int)floorf((mx - PCX) / GRIDSZ);
    int mvy = (int)floorf((my - PCY) / GRIDSZ);
    int mvz = (int)floorf((mz - PCZ) / GRIDSZ);
    float smax = fmaxf(scales[(size_t)g * 3 + 0],
                 fmaxf(scales[(size_t)g * 3 + 1], scales[(size_t)g * 3 + 2]));
    int r = (int)ceilf(smax * 3.0f / GRIDSZ);
    gbox[g] = make_int4(mvx - r, mvy - r, mvz - r, 2 * r);
    int cx0 = max(mvx - r, 0) >> 3, cx1 = min(mvx + r, VMAX) >> 3;
    int cy0 = max(mvy - r, 0) >> 3, cy1 = min(mvy + r, VMAX) >> 3;
    gcb[g] = (unsigned)cx0 | ((unsigned)cx1 << 8) | ((unsigned)cy0 << 16) | ((unsigned)cy1 << 24);
    gpay[(size_t)g * 3 + 0] = make_float4(mx, my, mz, opac[g]);
    gpay[(size_t)g * 3 + 1] = make_float4(M00 * inv, M01 * inv, M02 * inv,
                                          (c00 * c22 - c02 * c02) * inv);
    gpay[(size_t)g * 3 + 2] = make_float4((c01 * c02 - c00 * c12) * inv,
                                          (c00 * c11 - c01 * c01) * inv, 0.f, 0.f);
  } else if (id < M + N) {
    int p = id - M;
    float px = pts[(size_t)p * 3 + 0], py = pts[(size_t)p * 3 + 1], pz = pts[(size_t)p * 3 + 2];
    int pvx = (int)floorf((px - PCX) / GRIDSZ);
    int pvy = (int)floorf((py - PCY) / GRIDSZ);
    int pvz = (int)floorf((pz - PCZ) / GRIDSZ);
    unsigned cell = (unsigned)((pvx >> 3) + CELLS_X * (pvy >> 3));
    // 10b cell | 8b pvx | 8b pvy | 5b pvz  (pvz < 16 < 32)
    ppack[p] = cell | ((unsigned)pvx << 10) | ((unsigned)pvy << 18) | ((unsigned)pvz << 26);
    ppos[p] = make_float4(px, py, pz, __int_as_float(p));
  }
}

// Pass 2: one block per cell. Scan = int4 loads of 1-dword descriptors + masked
// compare (no divisions, no wide data). Compact via LDS atomics, rank-sort the
// candidates (deterministic FP order), prefetch all payloads in parallel, then
// the dense point x candidate loop runs entirely from LDS.
__global__ __launch_bounds__(256) void agg_kernel(
    const unsigned* __restrict__ ppack, const float4* __restrict__ ppos,
    const unsigned* __restrict__ gcb, const int4* __restrict__ gbox,
    const float4* __restrict__ gpay, const float* __restrict__ sem,
    float* __restrict__ out, int N, int M) {
  __shared__ int pcnt_s, gcnt_s;
  __shared__ unsigned lvox[PCAP];
  __shared__ int lpi[PCAP];
  __shared__ float4 lpts[PCAP];
  __shared__ int graw[GCAP];
  __shared__ int gsrt[GCAP];
  __shared__ int4 lbox[GCAP];
  __shared__ float4 lpay[GCAP * 3];
  __shared__ float lsem[GCAP * SEMW];
  __shared__ float buf[3][64][CCH + 1];  // +1 pad -> 19-word lane stride

  const int tid = threadIdx.x, lane = tid & 63, wave = tid >> 6;
  const unsigned cell = blockIdx.x;
  const int cx = (int)(cell % CELLS_X), cy = (int)(cell / CELLS_X);

  if (tid == 0) { pcnt_s = 0; gcnt_s = 0; }
  __syncthreads();

  // Phase A: point scan — N/4 uint4 descriptors, 10-bit cell compare.
  {
    const uint4* pp4 = reinterpret_cast<const uint4*>(ppack);
    const int n4 = N >> 2;
    for (int i4 = tid; i4 < n4; i4 += 256) {
      uint4 v = pp4[i4];
      unsigned pk[4] = {v.x, v.y, v.z, v.w};
#pragma unroll
      for (int k = 0; k < 4; ++k) {
        if ((pk[k] & 1023u) == cell) {
          int s = atomicAdd(&pcnt_s, 1);
          if (s < PCAP) { lvox[s] = pk[k]; lpi[s] = i4 * 4 + k; }
        }
      }
    }
    for (int i = (n4 << 2) + tid; i < N; i += 256) {  // tail (none for N=16384)
      unsigned pk = ppack[i];
      if ((pk & 1023u) == cell) {
        int s = atomicAdd(&pcnt_s, 1);
        if (s < PCAP) { lvox[s] = pk; lpi[s] = i; }
      }
    }
  }
  // Phase B: gaussian scan — M/4 uint4 cell-box descriptors.
  {
    const uint4* gb4 = reinterpret_cast<const uint4*>(gcb);
    const int m4 = M >> 2;
    for (int i4 = tid; i4 < m4; i4 += 256) {
      uint4 v = gb4[i4];
      unsigned gk[4] = {v.x, v.y, v.z, v.w};
#pragma unroll
      for (int k = 0; k < 4; ++k) {
        unsigned pk = gk[k];
        bool hit = (cx >= (int)(pk & 255u)) & (cx <= (int)((pk >> 8) & 255u)) &
                   (cy >= (int)((pk >> 16) & 255u)) & (cy <= (int)(pk >> 24));
        if (hit) {
          int s = atomicAdd(&gcnt_s, 1);
          if (s < GCAP) graw[s] = i4 * 4 + k;
        }
      }
    }
    for (int g = (m4 << 2) + tid; g < M; g += 256) {
      unsigned pk = gcb[g];
      bool hit = (cx >= (int)(pk & 255u)) & (cx <= (int)((pk >> 8) & 255u)) &
                 (cy >= (int)((pk >> 16) & 255u)) & (cy <= (int)(pk >> 24));
      if (hit) {
        int s = atomicAdd(&gcnt_s, 1);
        if (s < GCAP) graw[s] = g;
      }
    }
  }
  __syncthreads();
  const int P = min(pcnt_s, PCAP);
  const int K = min(gcnt_s, GCAP);

  // rank-sort candidates ascending: deterministic accumulation order
  if (tid < K) {
    int v = graw[tid], rank = 0;
    for (int j = 0; j < K; ++j) rank += (graw[j] < v);
    gsrt[rank] = v;
  }
  __syncthreads();

  // Parallel prefetch: points + all candidate payloads (latency paid once).
  if (tid < P) lpts[tid] = ppos[lpi[tid]];
  for (int j = tid; j < K; j += 256) lbox[j] = gbox[gsrt[j]];
  for (int idx = tid; idx < K * 3; idx += 256) {
    int j = idx / 3, k = idx - j * 3;
    lpay[idx] = gpay[(size_t)gsrt[j] * 3 + k];
  }
  for (int idx = tid; idx < K * CCH; idx += 256) {
    int j = idx / CCH, c2 = idx - j * CCH;
    lsem[j * SEMW + c2] = sem[(size_t)gsrt[j] * CCH + c2];
  }
  __syncthreads();

  const int kq = (K + 3) >> 2;          // candidates per wave (sorted quarters)
  const int j0 = wave * kq, j1 = min(K, j0 + kq);

  for (int pb = 0; pb < P; pb += 64) {
    const bool vp = (pb + lane) < P;
    const float4 pt = lpts[vp ? pb + lane : 0];
    const unsigned pk = vp ? lvox[pb + lane] : 0u;
    int pvx = (int)((pk >> 10) & 255u);
    int pvy = (int)((pk >> 18) & 255u);
    int pvz = (int)(pk >> 26);
    if (!vp) pvx = -100000;  // fails every box

    float acc[CCH];
#pragma unroll
    for (int c = 0; c < CCH; ++c) acc[c] = 0.f;

    for (int j = j0; j < j1; ++j) {
      int4 bx = lbox[j];  // uniform -> LDS broadcast
      bool m = ((unsigned)(pvx - bx.x) <= (unsigned)bx.w) &
               ((unsigned)(pvy - bx.y) <= (unsigned)bx.w) &
               ((unsigned)(pvz - bx.z) <= (unsigned)bx.w);
      if (__any(m)) {
        float4 q0 = lpay[j * 3 + 0];
        float4 q1 = lpay[j * 3 + 1];
        float4 q2 = lpay[j * 3 + 2];
        float dx = pt.x - q0.x, dy = pt.y - q0.y, dz = pt.z - q0.z;
        float t0 = q1.x * dx + q1.y * dy + q1.z * dz;
        float t1 = q1.y * dx + q1.w * dy + q2.x * dz;
        float t2 = q1.z * dx + q2.x * dy + q2.y * dz;
        float qq = dx * t0 + dy * t1 + dz * t2;
        float w = m ? __expf(-0.5f * qq) * q0.w : 0.f;
        const float4* s4 = reinterpret_cast<const float4*>(&lsem[j * SEMW]);
        float4 sa = s4[0], sb = s4[1], sc = s4[2], sd = s4[3];
        float2 se = *reinterpret_cast<const float2*>(&lsem[j * SEMW + 16]);
        acc[0]  = fmaf(w, sa.x, acc[0]);  acc[1]  = fmaf(w, sa.y, acc[1]);
        acc[2]  = fmaf(w, sa.z, acc[2]);  acc[3]  = fmaf(w, sa.w, acc[3]);
        acc[4]  = fmaf(w, sb.x, acc[4]);  acc[5]  = fmaf(w, sb.y, acc[5]);
        acc[6]  = fmaf(w, sb.z, acc[6]);  acc[7]  = fmaf(w, sb.w, acc[7]);
        acc[8]  = fmaf(w, sc.x, acc[8]);  acc[9]  = fmaf(w, sc.y, acc[9]);
        acc[10] = fmaf(w, sc.z, acc[10]); acc[11] = fmaf(w, sc.w, acc[11]);
        acc[12] = fmaf(w, sd.x, acc[12]); acc[13] = fmaf(w, sd.y, acc[13]);
        acc[14] = fmaf(w, sd.z, acc[14]); acc[15] = fmaf(w, sd.w, acc[15]);
        acc[16] = fmaf(w, se.x, acc[16]); acc[17] = fmaf(w, se.y, acc[17]);
      }
    }

    // deterministic cross-wave reduce, one write per point
    if (wave > 0) {
#pragma unroll
      for (int c = 0; c < CCH; ++c) buf[wave - 1][lane][c] = acc[c];
    }
    __syncthreads();
    if (wave == 0 && vp) {
      int myp = __float_as_int(pt.w);
      float* o = out + (size_t)myp * CCH;
#pragma unroll
      for (int c = 0; c < CCH; ++c)
        o[c] = acc[c] + buf[0][lane][c] + buf[1][lane][c] + buf[2][lane][c];
    }
    __syncthreads();  // buf reused by next point-chunk
  }
}

extern "C" void kernel_launch(void* const* d_in, const int* in_sizes, int n_in,
                              void* d_out, int out_size, void* d_ws, size_t ws_size,
                              hipStream_t stream) {
  const float* pts     = (const float*)d_in[0];
  const float* means3D = (const float*)d_in[1];
  const float* opac    = (const float*)d_in[2];
  const float* sem     = (const float*)d_in[3];
  const float* scales  = (const float*)d_in[4];
  const float* cov3D   = (const float*)d_in[5];
  float* out = (float*)d_out;

  int N = in_sizes[0] / 3;
  int M = in_sizes[1] / 3;

  char* ws = (char*)d_ws;
  size_t off = 0;
  auto alloc = [&](size_t bytes) { char* p = ws + off; off = (off + bytes + 255) & ~(size_t)255; return p; };
  unsigned* ppack = (unsigned*)alloc((size_t)N * 4);
  float4*   ppos  = (float4*)alloc((size_t)N * 16);
  unsigned* gcb   = (unsigned*)alloc((size_t)M * 4);
  int4*     gbox  = (int4*)alloc((size_t)M * 16);
  float4*   gpay  = (float4*)alloc((size_t)M * 48);

  prep_kernel<<<(N + M + 255) / 256, 256, 0, stream>>>(
      pts, means3D, opac, scales, cov3D, ppack, ppos, gcb, gbox, gpay, N, M);

  agg_kernel<<<NCELLS, 256, 0, stream>>>(
      ppack, ppos, gcb, gbox, gpay, sem, out, N, M);
}